// Round 3
// baseline (49.137 us; speedup 1.0000x reference)
//
#include <hip/hip_runtime.h>
#include <hip/hip_bf16.h>

#define IN_F 8192
#define OUT_F 8192
#define BATCH 64

typedef __attribute__((ext_vector_type(8))) short bf16x8_t;  // 8 bf16 (4 VGPRs)
typedef __attribute__((ext_vector_type(4))) float f32x4_t;   // MFMA accumulator

// ---------------------------------------------------------------------------
// out[r][c] = bias[c]  (K-split GEMM accumulates on top via atomics)
// ---------------------------------------------------------------------------
__global__ void wol_init_out(const float* __restrict__ bias,
                             float* __restrict__ out) {
    int idx = blockIdx.x * 256 + threadIdx.x;
    if (idx < BATCH * OUT_F) out[idx] = bias[idx & (OUT_F - 1)];
}

// ---------------------------------------------------------------------------
// x fp32 [64][8192] -> xb bf16, fragment-major: xb[(k8*64 + row)*8 + j]
// (k8 = k/8). A-fragment load in GEMM is then a single 16B/lane read.
// ---------------------------------------------------------------------------
__global__ void wol_xconv(const float* __restrict__ x,
                          ushort* __restrict__ xb) {
    int g = blockIdx.x * 256 + threadIdx.x;   // 65536 threads
    int k8  = g & 1023;
    int row = g >> 10;
    const float4* src = (const float4*)&x[row * IN_F + k8 * 8];
    float4 a = src[0], b = src[1];
    float f[8] = {a.x, a.y, a.z, a.w, b.x, b.y, b.z, b.w};
    union { ushort u[8]; bf16x8_t v; } o;
#pragma unroll
    for (int j = 0; j < 8; ++j) {
        __hip_bfloat16 hb = __float2bfloat16(f[j]);
        o.u[j] = *reinterpret_cast<ushort*>(&hb);
    }
    *(bf16x8_t*)&xb[((size_t)k8 * 64 + row) * 8] = o.v;
}

// ---------------------------------------------------------------------------
// MFMA GEMM, in-register dequant, no LDS, no barriers.
// Grid: 32 N-tiles (256 cols) x 16 K-splits (512 K) = 512 blocks x 512 thr.
// Wave w = 0..7 owns cols [nt*256 + w*32 .. +32), full block K range.
// Wave tile 64x32: 4 M-frags x 2 N-frags of mfma_f32_16x16x32_bf16.
// One qweight int32 per lane = one B-fragment K-slice (8 nibbles).
// All 8 q-words of a 128-K group issue upfront for HBM latency tolerance.
// ---------------------------------------------------------------------------
__global__ void __launch_bounds__(512, 4)
wol_mfma(const int*    __restrict__ qw,
         const int*    __restrict__ qz,
         const float*  __restrict__ sc,
         const ushort* __restrict__ xb,
         float*        __restrict__ out) {
    const int nt   = blockIdx.x & 31;
    const int ks   = blockIdx.x >> 5;
    const int wid  = threadIdx.x >> 6;
    const int lane = threadIdx.x & 63;
    const int ln   = lane & 15;
    const int kb   = lane >> 4;                 // k-subblock 0..3
    const int colbase = nt * 256 + wid * 32;    // wave's 32 columns
    const int k0      = ks * 512;               // wave K range (4 groups)
    const int gbase   = k0 >> 7;

    f32x4_t acc[4][2];
#pragma unroll
    for (int mi = 0; mi < 4; ++mi)
#pragma unroll
        for (int nj = 0; nj < 2; ++nj) acc[mi][nj] = (f32x4_t)0.0f;

#pragma unroll 1
    for (int g = 0; g < 4; ++g) {               // 4 quant groups of 128 K
        const int gg = gbase + g;
        float s[2], dz[2];
#pragma unroll
        for (int nj = 0; nj < 2; ++nj) {
            const int c = colbase + nj * 16 + ln;
            const float sv = sc[gg * OUT_F + c];
            const unsigned z = (unsigned)qz[gg * (OUT_F / 8) + (c >> 3)];
            const unsigned zp = ((z >> ((c & 7) * 4)) + 1u) & 15u;  // stored zp-1
            s[nj] = sv;
            dz[nj] = -(float)zp * sv;           // w = nib*s + dz
        }
        const int qrow0 = (k0 + g * 128) >> 3;  // 16 packed rows this group

        // ---- issue all 8 HBM loads for this group upfront ----
        unsigned q[4][2];
#pragma unroll
        for (int kt = 0; kt < 4; ++kt)
#pragma unroll
            for (int nj = 0; nj < 2; ++nj)
                q[kt][nj] = (unsigned)qw[(size_t)(qrow0 + kt * 4 + kb) * OUT_F +
                                         colbase + nj * 16 + ln];

#pragma unroll
        for (int kt = 0; kt < 4; ++kt) {        // 4 K-steps of 32
            const int qrow = qrow0 + kt * 4 + kb;
            bf16x8_t af[4];
#pragma unroll
            for (int mi = 0; mi < 4; ++mi)
                af[mi] = *(const bf16x8_t*)&xb[((size_t)qrow * 64 + mi * 16 + ln) * 8];
#pragma unroll
            for (int nj = 0; nj < 2; ++nj) {
                const unsigned qv  = q[kt][nj];
                const unsigned qlo = qv & 0x0F0F0F0Fu;         // nibbles 0,2,4,6
                const unsigned qhi = (qv >> 4) & 0x0F0F0F0Fu;  // nibbles 1,3,5,7
                union { ushort u[8]; bf16x8_t v; } bu;
#pragma unroll
                for (int b = 0; b < 4; ++b) {
                    // byte extracts -> v_cvt_f32_ubyte{0..3}
                    const float fe = (float)((qlo >> (8 * b)) & 0xFFu);
                    const float fo = (float)((qhi >> (8 * b)) & 0xFFu);
                    const float we = fe * s[nj] + dz[nj];
                    const float wo = fo * s[nj] + dz[nj];
                    __hip_bfloat16 he = __float2bfloat16(we);
                    __hip_bfloat16 ho = __float2bfloat16(wo);
                    bu.u[2 * b]     = *reinterpret_cast<ushort*>(&he);
                    bu.u[2 * b + 1] = *reinterpret_cast<ushort*>(&ho);
                }
#pragma unroll
                for (int mi = 0; mi < 4; ++mi)
                    acc[mi][nj] = __builtin_amdgcn_mfma_f32_16x16x32_bf16(
                        af[mi], bu.v, acc[mi][nj], 0, 0, 0);
            }
        }
    }

    // ---- epilogue: fp32 atomics onto bias-initialized out ----
#pragma unroll
    for (int mi = 0; mi < 4; ++mi)
#pragma unroll
        for (int nj = 0; nj < 2; ++nj)
#pragma unroll
            for (int j = 0; j < 4; ++j) {
                const int row = mi * 16 + kb * 4 + j;      // C/D layout (m89)
                const int col = colbase + nj * 16 + ln;
                atomicAdd(&out[(size_t)row * OUT_F + col], acc[mi][nj][j]);
            }
}

extern "C" void kernel_launch(void* const* d_in, const int* in_sizes, int n_in,
                              void* d_out, int out_size, void* d_ws, size_t ws_size,
                              hipStream_t stream) {
    const float* x    = (const float*)d_in[0];
    const int*   qw   = (const int*)d_in[1];
    const int*   qz   = (const int*)d_in[2];
    const float* sc   = (const float*)d_in[3];
    const float* bias = (const float*)d_in[4];
    float*  out = (float*)d_out;
    ushort* xb  = (ushort*)d_ws;              // 1 MiB bf16 activations

    (void)in_sizes; (void)n_in; (void)ws_size; (void)out_size;

    wol_init_out<<<(BATCH * OUT_F + 255) / 256, 256, 0, stream>>>(bias, out);
    wol_xconv<<<256, 256, 0, stream>>>(x, xb);
    wol_mfma<<<512, 512, 0, stream>>>(qw, qz, sc, xb, out);
}

// Round 4
// 45.917 us; speedup vs baseline: 1.0701x; 1.0701x over previous
//
#include <hip/hip_runtime.h>
#include <hip/hip_bf16.h>

#define IN_F 8192
#define OUT_F 8192
#define BATCH 64

typedef __attribute__((ext_vector_type(8))) short bf16x8_t;  // 8 bf16 (4 VGPRs)
typedef __attribute__((ext_vector_type(4))) float f32x4_t;   // MFMA accumulator

// ---------------------------------------------------------------------------
// out[r][c] = bias[c]  (K-split GEMM accumulates on top via atomics)
// ---------------------------------------------------------------------------
__global__ void wol_init_out(const float* __restrict__ bias,
                             float* __restrict__ out) {
    int idx = blockIdx.x * 256 + threadIdx.x;
    if (idx < BATCH * OUT_F) out[idx] = bias[idx & (OUT_F - 1)];
}

// ---------------------------------------------------------------------------
// x fp32 [64][8192] -> xb bf16, fragment-major: xb[(k8*64 + row)*8 + j]
// ---------------------------------------------------------------------------
__global__ void wol_xconv(const float* __restrict__ x,
                          ushort* __restrict__ xb) {
    int g = blockIdx.x * 256 + threadIdx.x;   // 65536 threads
    int k8  = g & 1023;
    int row = g >> 10;
    const float4* src = (const float4*)&x[row * IN_F + k8 * 8];
    float4 a = src[0], b = src[1];
    float f[8] = {a.x, a.y, a.z, a.w, b.x, b.y, b.z, b.w};
    union { ushort u[8]; bf16x8_t v; } o;
#pragma unroll
    for (int j = 0; j < 8; ++j) {
        __hip_bfloat16 hb = __float2bfloat16(f[j]);
        o.u[j] = *reinterpret_cast<ushort*>(&hb);
    }
    *(bf16x8_t*)&xb[((size_t)k8 * 64 + row) * 8] = o.v;
}

// ---------------------------------------------------------------------------
// MFMA GEMM, in-register dequant, A-fragments staged in LDS per block.
// Grid: 32 N-tiles (256 cols) x 16 K-splits (512 K) = 512 blocks x 512 thr
//       = exactly 2 blocks/CU (2 x 64KB LDS fits 160KB).
// Wave w owns cols [nt*256 + w*32), full block K range (4 quant groups).
// Wave tile 64x32: 4 M-frags x 2 N-frags of mfma_f32_16x16x32_bf16.
// One qweight int32 per lane = one B-fragment K-slice (8 nibbles).
// Group loop fully unrolled -> compiler hoists q loads for MLP.
// ---------------------------------------------------------------------------
__global__ void __launch_bounds__(512, 4)
wol_mfma(const int*    __restrict__ qw,
         const int*    __restrict__ qz,
         const float*  __restrict__ sc,
         const ushort* __restrict__ xb,
         float*        __restrict__ out) {
    const int nt   = blockIdx.x & 31;
    const int ks   = blockIdx.x >> 5;
    const int wid  = threadIdx.x >> 6;
    const int lane = threadIdx.x & 63;
    const int ln   = lane & 15;
    const int kb   = lane >> 4;                 // k-subblock 0..3
    const int colbase = nt * 256 + wid * 32;    // wave's 32 columns
    const int k0      = ks * 512;               // block K range (4 groups)
    const int gbase   = k0 >> 7;

    // ---- stage this block's A fragments: 64 qrows x 64 rows x 8 bf16 = 64KB
    __shared__ ushort lds_x[64 * 64 * 8];
    {
        const bf16x8_t* src = (const bf16x8_t*)xb + (size_t)ks * 4096;
        bf16x8_t*       dst = (bf16x8_t*)lds_x;
#pragma unroll
        for (int i = 0; i < 8; ++i)
            dst[i * 512 + threadIdx.x] = src[i * 512 + threadIdx.x];
    }
    __syncthreads();

    f32x4_t acc[4][2];
#pragma unroll
    for (int mi = 0; mi < 4; ++mi)
#pragma unroll
        for (int nj = 0; nj < 2; ++nj) acc[mi][nj] = (f32x4_t)0.0f;

#pragma unroll
    for (int g = 0; g < 4; ++g) {               // 4 quant groups of 128 K
        const int gg = gbase + g;
        float s[2], dz[2];
#pragma unroll
        for (int nj = 0; nj < 2; ++nj) {
            const int c = colbase + nj * 16 + ln;
            const float sv = sc[gg * OUT_F + c];
            const unsigned z = (unsigned)qz[gg * (OUT_F / 8) + (c >> 3)];
            const unsigned zp = ((z >> ((c & 7) * 4)) + 1u) & 15u;  // stored zp-1
            s[nj] = sv;
            dz[nj] = -(float)zp * sv;           // w = nib*s + dz
        }
        const int qrow0 = (k0 >> 3) + g * 16;

        unsigned q[4][2];
#pragma unroll
        for (int kt = 0; kt < 4; ++kt)
#pragma unroll
            for (int nj = 0; nj < 2; ++nj)
                q[kt][nj] = (unsigned)qw[(size_t)(qrow0 + kt * 4 + kb) * OUT_F +
                                         colbase + nj * 16 + ln];

#pragma unroll
        for (int kt = 0; kt < 4; ++kt) {        // 4 K-steps of 32
            const int lrow = g * 16 + kt * 4 + kb;   // local qrow 0..63
            bf16x8_t af[4];
#pragma unroll
            for (int mi = 0; mi < 4; ++mi)
                af[mi] = *(const bf16x8_t*)&lds_x[(lrow * 64 + mi * 16 + ln) * 8];
#pragma unroll
            for (int nj = 0; nj < 2; ++nj) {
                const unsigned qv  = q[kt][nj];
                const unsigned qlo = qv & 0x0F0F0F0Fu;         // nibbles 0,2,4,6
                const unsigned qhi = (qv >> 4) & 0x0F0F0F0Fu;  // nibbles 1,3,5,7
                union { ushort u[8]; bf16x8_t v; } bu;
#pragma unroll
                for (int b = 0; b < 4; ++b) {
                    const float fe = (float)((qlo >> (8 * b)) & 0xFFu);  // v_cvt_f32_ubyteN
                    const float fo = (float)((qhi >> (8 * b)) & 0xFFu);
                    const float we = fe * s[nj] + dz[nj];
                    const float wo = fo * s[nj] + dz[nj];
                    __hip_bfloat16 he = __float2bfloat16(we);
                    __hip_bfloat16 ho = __float2bfloat16(wo);
                    bu.u[2 * b]     = *reinterpret_cast<ushort*>(&he);
                    bu.u[2 * b + 1] = *reinterpret_cast<ushort*>(&ho);
                }
#pragma unroll
                for (int mi = 0; mi < 4; ++mi)
                    acc[mi][nj] = __builtin_amdgcn_mfma_f32_16x16x32_bf16(
                        af[mi], bu.v, acc[mi][nj], 0, 0, 0);
            }
        }
    }

    // ---- epilogue: fp32 atomics onto bias-initialized out ----
#pragma unroll
    for (int mi = 0; mi < 4; ++mi)
#pragma unroll
        for (int nj = 0; nj < 2; ++nj)
#pragma unroll
            for (int j = 0; j < 4; ++j) {
                const int row = mi * 16 + kb * 4 + j;      // C/D layout (m89)
                const int col = colbase + nj * 16 + ln;
                atomicAdd(&out[(size_t)row * OUT_F + col], acc[mi][nj][j]);
            }
}

extern "C" void kernel_launch(void* const* d_in, const int* in_sizes, int n_in,
                              void* d_out, int out_size, void* d_ws, size_t ws_size,
                              hipStream_t stream) {
    const float* x    = (const float*)d_in[0];
    const int*   qw   = (const int*)d_in[1];
    const int*   qz   = (const int*)d_in[2];
    const float* sc   = (const float*)d_in[3];
    const float* bias = (const float*)d_in[4];
    float*  out = (float*)d_out;
    ushort* xb  = (ushort*)d_ws;              // 1 MiB bf16 activations

    (void)in_sizes; (void)n_in; (void)ws_size; (void)out_size;

    wol_init_out<<<(BATCH * OUT_F + 255) / 256, 256, 0, stream>>>(bias, out);
    wol_xconv<<<256, 256, 0, stream>>>(x, xb);
    wol_mfma<<<512, 512, 0, stream>>>(qw, qz, sc, xb, out);
}

// Round 5
// 34.506 us; speedup vs baseline: 1.4240x; 1.3307x over previous
//
#include <hip/hip_runtime.h>
#include <hip/hip_bf16.h>

#define IN_F 8192
#define OUT_F 8192
#define BATCH 64
#define KSPLIT 16

typedef __attribute__((ext_vector_type(8))) short bf16x8_t;  // 8 bf16 (4 VGPRs)
typedef __attribute__((ext_vector_type(4))) float f32x4_t;   // MFMA accumulator

// ---------------------------------------------------------------------------
// x fp32 [64][8192] -> xb bf16, fragment-major: xb[(k8*64 + row)*8 + j]
// ---------------------------------------------------------------------------
__global__ void wol_xconv(const float* __restrict__ x,
                          ushort* __restrict__ xb) {
    int g = blockIdx.x * 256 + threadIdx.x;   // 65536 threads
    int k8  = g & 1023;
    int row = g >> 10;
    const float4* src = (const float4*)&x[row * IN_F + k8 * 8];
    float4 a = src[0], b = src[1];
    float f[8] = {a.x, a.y, a.z, a.w, b.x, b.y, b.z, b.w};
    union { ushort u[8]; bf16x8_t v; } o;
#pragma unroll
    for (int j = 0; j < 8; ++j) {
        __hip_bfloat16 hb = __float2bfloat16(f[j]);
        o.u[j] = *reinterpret_cast<ushort*>(&hb);
    }
    *(bf16x8_t*)&xb[((size_t)k8 * 64 + row) * 8] = o.v;
}

// ---------------------------------------------------------------------------
// Stage A: MFMA GEMM, in-register dequant, A staged in LDS, NO ATOMICS.
// Grid: 32 N-tiles (256 cols) x 16 K-splits (512 K) = 512 blocks x 512 thr.
// Wave w owns cols [nt*256 + w*32), block K range (4 quant groups).
// Writes fp32 partials to part[ks][64][8192] with plain coalesced-ish
// stores (each address written exactly once chip-wide).
// ---------------------------------------------------------------------------
__global__ void __launch_bounds__(512, 4)
wol_mfma(const int*    __restrict__ qw,
         const int*    __restrict__ qz,
         const float*  __restrict__ sc,
         const ushort* __restrict__ xb,
         float*        __restrict__ part) {
    const int nt   = blockIdx.x & 31;
    const int ks   = blockIdx.x >> 5;
    const int wid  = threadIdx.x >> 6;
    const int lane = threadIdx.x & 63;
    const int ln   = lane & 15;
    const int kb   = lane >> 4;                 // k-subblock 0..3
    const int colbase = nt * 256 + wid * 32;    // wave's 32 columns
    const int k0      = ks * 512;               // block K range (4 groups)
    const int gbase   = k0 >> 7;

    // ---- stage block's A fragments: 64 qrows x 64 rows x 8 bf16 = 64KB ----
    __shared__ ushort lds_x[64 * 64 * 8];
    {
        const bf16x8_t* src = (const bf16x8_t*)xb + (size_t)ks * 4096;
        bf16x8_t*       dst = (bf16x8_t*)lds_x;
#pragma unroll
        for (int i = 0; i < 8; ++i)
            dst[i * 512 + threadIdx.x] = src[i * 512 + threadIdx.x];
    }
    __syncthreads();

    f32x4_t acc[4][2];
#pragma unroll
    for (int mi = 0; mi < 4; ++mi)
#pragma unroll
        for (int nj = 0; nj < 2; ++nj) acc[mi][nj] = (f32x4_t)0.0f;

#pragma unroll
    for (int g = 0; g < 4; ++g) {               // 4 quant groups of 128 K
        const int gg = gbase + g;
        float s[2], dz[2];
#pragma unroll
        for (int nj = 0; nj < 2; ++nj) {
            const int c = colbase + nj * 16 + ln;
            const float sv = sc[gg * OUT_F + c];
            const unsigned z = (unsigned)qz[gg * (OUT_F / 8) + (c >> 3)];
            const unsigned zp = ((z >> ((c & 7) * 4)) + 1u) & 15u;  // stored zp-1
            s[nj] = sv;
            dz[nj] = -(float)zp * sv;           // w = nib*s + dz
        }
        const int qrow0 = (k0 >> 3) + g * 16;

        unsigned q[4][2];
#pragma unroll
        for (int kt = 0; kt < 4; ++kt)
#pragma unroll
            for (int nj = 0; nj < 2; ++nj)
                q[kt][nj] = (unsigned)qw[(size_t)(qrow0 + kt * 4 + kb) * OUT_F +
                                         colbase + nj * 16 + ln];

#pragma unroll
        for (int kt = 0; kt < 4; ++kt) {        // 4 K-steps of 32
            const int lrow = g * 16 + kt * 4 + kb;   // local qrow 0..63
            bf16x8_t af[4];
#pragma unroll
            for (int mi = 0; mi < 4; ++mi)
                af[mi] = *(const bf16x8_t*)&lds_x[(lrow * 64 + mi * 16 + ln) * 8];
#pragma unroll
            for (int nj = 0; nj < 2; ++nj) {
                const unsigned qv  = q[kt][nj];
                const unsigned qlo = qv & 0x0F0F0F0Fu;         // nibbles 0,2,4,6
                const unsigned qhi = (qv >> 4) & 0x0F0F0F0Fu;  // nibbles 1,3,5,7
                union { ushort u[8]; bf16x8_t v; } bu;
#pragma unroll
                for (int b = 0; b < 4; ++b) {
                    const float fe = (float)((qlo >> (8 * b)) & 0xFFu);  // v_cvt_f32_ubyteN
                    const float fo = (float)((qhi >> (8 * b)) & 0xFFu);
                    const float we = fe * s[nj] + dz[nj];
                    const float wo = fo * s[nj] + dz[nj];
                    __hip_bfloat16 he = __float2bfloat16(we);
                    __hip_bfloat16 ho = __float2bfloat16(wo);
                    bu.u[2 * b]     = *reinterpret_cast<ushort*>(&he);
                    bu.u[2 * b + 1] = *reinterpret_cast<ushort*>(&ho);
                }
#pragma unroll
                for (int mi = 0; mi < 4; ++mi)
                    acc[mi][nj] = __builtin_amdgcn_mfma_f32_16x16x32_bf16(
                        af[mi], bu.v, acc[mi][nj], 0, 0, 0);
            }
        }
    }

    // ---- epilogue: plain fp32 partial stores (no contention) ----
    float* pbase = part + (size_t)ks * (BATCH * OUT_F);
#pragma unroll
    for (int mi = 0; mi < 4; ++mi)
#pragma unroll
        for (int nj = 0; nj < 2; ++nj)
#pragma unroll
            for (int j = 0; j < 4; ++j) {
                const int row = mi * 16 + kb * 4 + j;      // C/D layout (m89)
                const int col = colbase + nj * 16 + ln;
                pbase[(size_t)row * OUT_F + col] = acc[mi][nj][j];
            }
}

// ---------------------------------------------------------------------------
// Stage B: out[row][col] = sum_ks part[ks][row][col] + bias[col]
// float4 per thread, fully coalesced.
// ---------------------------------------------------------------------------
__global__ void __launch_bounds__(256)
wol_reduce(const float* __restrict__ part,
           const float* __restrict__ bias,
           float* __restrict__ out) {
    const int idx = blockIdx.x * 256 + threadIdx.x;        // float4 index
    const int flat = idx * 4;
    const int col  = flat & (OUT_F - 1);
    const int row  = flat >> 13;
    float4 acc = *(const float4*)&bias[col];
#pragma unroll
    for (int ks = 0; ks < KSPLIT; ++ks) {
        const float4 p = *(const float4*)&part[((size_t)ks * BATCH + row) * OUT_F + col];
        acc.x += p.x; acc.y += p.y; acc.z += p.z; acc.w += p.w;
    }
    *(float4*)&out[(size_t)row * OUT_F + col] = acc;
}

extern "C" void kernel_launch(void* const* d_in, const int* in_sizes, int n_in,
                              void* d_out, int out_size, void* d_ws, size_t ws_size,
                              hipStream_t stream) {
    const float* x    = (const float*)d_in[0];
    const int*   qw   = (const int*)d_in[1];
    const int*   qz   = (const int*)d_in[2];
    const float* sc   = (const float*)d_in[3];
    const float* bias = (const float*)d_in[4];
    float* out = (float*)d_out;

    ushort* xb   = (ushort*)d_ws;                          // 1 MiB bf16 activations
    float*  prt  = (float*)((char*)d_ws + (16u << 20));    // 32 MiB fp32 partials

    (void)in_sizes; (void)n_in; (void)ws_size; (void)out_size;

    wol_xconv<<<256, 256, 0, stream>>>(x, xb);
    wol_mfma<<<512, 512, 0, stream>>>(qw, qz, sc, xb, prt);
    wol_reduce<<<(BATCH * OUT_F / 4) / 256, 256, 0, stream>>>(prt, bias, out);
}

// Round 6
// 32.214 us; speedup vs baseline: 1.5253x; 1.0712x over previous
//
#include <hip/hip_runtime.h>
#include <hip/hip_bf16.h>

#define IN_F 8192
#define OUT_F 8192
#define BATCH 64
#define KSPLIT 16

typedef __attribute__((ext_vector_type(8))) short  bf16x8_t;  // 8 bf16 (4 VGPRs)
typedef __attribute__((ext_vector_type(8))) ushort u16x8_t;   // 16B store unit
typedef __attribute__((ext_vector_type(4))) float  f32x4_t;   // MFMA accumulator

// ---------------------------------------------------------------------------
// x fp32 [64][8192] -> xb bf16, fragment-major: xb[(k8*64 + row)*8 + j]
// ---------------------------------------------------------------------------
__global__ void wol_xconv(const float* __restrict__ x,
                          ushort* __restrict__ xb) {
    int g = blockIdx.x * 256 + threadIdx.x;   // 65536 threads
    int k8  = g & 1023;
    int row = g >> 10;
    const float4* src = (const float4*)&x[row * IN_F + k8 * 8];
    float4 a = src[0], b = src[1];
    float f[8] = {a.x, a.y, a.z, a.w, b.x, b.y, b.z, b.w};
    union { ushort u[8]; bf16x8_t v; } o;
#pragma unroll
    for (int j = 0; j < 8; ++j) {
        __hip_bfloat16 hb = __float2bfloat16(f[j]);
        o.u[j] = *reinterpret_cast<ushort*>(&hb);
    }
    *(bf16x8_t*)&xb[((size_t)k8 * 64 + row) * 8] = o.v;
}

// ---------------------------------------------------------------------------
// Stage A: MFMA GEMM, in-register dequant, A staged in LDS, no atomics.
// Grid: 32 N-tiles x 16 K-splits = 512 blocks x 512 thr (2 blocks/CU).
// Cross-group software pipeline: group g+1's qweight/scale/zero loads are
// issued BEFORE group g's compute (rotating register buffers, all static
// indexing). Group-0 loads issue before LDS staging.
// Partials: bf16, fragment-major: part[((ks*32+nt)*512+tid)*32 + idx],
// idx = (mi*2+nj)*4 + j  -> one 64B contiguous store per thread.
// ---------------------------------------------------------------------------
__global__ void __launch_bounds__(512, 4)
wol_mfma(const int*    __restrict__ qw,
         const int*    __restrict__ qz,
         const float*  __restrict__ sc,
         const ushort* __restrict__ xb,
         ushort*       __restrict__ part) {
    const int nt   = blockIdx.x & 31;
    const int ks   = blockIdx.x >> 5;
    const int wid  = threadIdx.x >> 6;
    const int lane = threadIdx.x & 63;
    const int ln   = lane & 15;
    const int kb   = lane >> 4;                 // k-subblock 0..3
    const int colbase = nt * 256 + wid * 32;    // wave's 32 columns
    const int k0      = ks * 512;               // block K range (4 groups)
    const int gbase   = k0 >> 7;
    const int qrowb   = k0 >> 3;

    // ---- group-0 prefetch (in flight across LDS staging + barrier) ----
    unsigned qc[4][2]; float svc[2]; unsigned zwc[2];
#pragma unroll
    for (int kt = 0; kt < 4; ++kt)
#pragma unroll
        for (int nj = 0; nj < 2; ++nj)
            qc[kt][nj] = (unsigned)qw[(size_t)(qrowb + kt * 4 + kb) * OUT_F +
                                      colbase + nj * 16 + ln];
#pragma unroll
    for (int nj = 0; nj < 2; ++nj) {
        const int c = colbase + nj * 16 + ln;
        svc[nj] = sc[gbase * OUT_F + c];
        zwc[nj] = (unsigned)qz[gbase * (OUT_F / 8) + (c >> 3)];
    }

    // ---- stage block's A fragments: 64 qrows x 64 rows x 8 bf16 = 64KB ----
    __shared__ ushort lds_x[64 * 64 * 8];
    {
        const bf16x8_t* src = (const bf16x8_t*)xb + (size_t)ks * 4096;
        bf16x8_t*       dst = (bf16x8_t*)lds_x;
#pragma unroll
        for (int i = 0; i < 8; ++i)
            dst[i * 512 + threadIdx.x] = src[i * 512 + threadIdx.x];
    }
    __syncthreads();

    f32x4_t acc[4][2];
#pragma unroll
    for (int mi = 0; mi < 4; ++mi)
#pragma unroll
        for (int nj = 0; nj < 2; ++nj) acc[mi][nj] = (f32x4_t)0.0f;

#pragma unroll
    for (int g = 0; g < 4; ++g) {               // 4 quant groups of 128 K
        // ---- prefetch group g+1 before computing group g ----
        unsigned qn[4][2]; float svn[2]; unsigned zwn[2];
        if (g < 3) {
            const int qrow1 = qrowb + (g + 1) * 16;
#pragma unroll
            for (int kt = 0; kt < 4; ++kt)
#pragma unroll
                for (int nj = 0; nj < 2; ++nj)
                    qn[kt][nj] = (unsigned)qw[(size_t)(qrow1 + kt * 4 + kb) * OUT_F +
                                              colbase + nj * 16 + ln];
#pragma unroll
            for (int nj = 0; nj < 2; ++nj) {
                const int c = colbase + nj * 16 + ln;
                svn[nj] = sc[(gbase + g + 1) * OUT_F + c];
                zwn[nj] = (unsigned)qz[(gbase + g + 1) * (OUT_F / 8) + (c >> 3)];
            }
        }

        float s[2], dz[2];
#pragma unroll
        for (int nj = 0; nj < 2; ++nj) {
            const unsigned zp = ((zwc[nj] >> ((ln & 7) * 4)) + 1u) & 15u;  // zp-1 stored
            s[nj]  = svc[nj];
            dz[nj] = -(float)zp * svc[nj];      // w = nib*s + dz
        }

#pragma unroll
        for (int kt = 0; kt < 4; ++kt) {        // 4 K-steps of 32
            const int lrow = g * 16 + kt * 4 + kb;   // local qrow 0..63
            bf16x8_t af[4];
#pragma unroll
            for (int mi = 0; mi < 4; ++mi)
                af[mi] = *(const bf16x8_t*)&lds_x[(lrow * 64 + mi * 16 + ln) * 8];
#pragma unroll
            for (int nj = 0; nj < 2; ++nj) {
                const unsigned qv  = qc[kt][nj];
                const unsigned qlo = qv & 0x0F0F0F0Fu;         // nibbles 0,2,4,6
                const unsigned qhi = (qv >> 4) & 0x0F0F0F0Fu;  // nibbles 1,3,5,7
                union { ushort u[8]; bf16x8_t v; } bu;
#pragma unroll
                for (int b = 0; b < 4; ++b) {
                    const float fe = (float)((qlo >> (8 * b)) & 0xFFu);  // v_cvt_f32_ubyteN
                    const float fo = (float)((qhi >> (8 * b)) & 0xFFu);
                    const float we = fe * s[nj] + dz[nj];
                    const float wo = fo * s[nj] + dz[nj];
                    __hip_bfloat16 he = __float2bfloat16(we);
                    __hip_bfloat16 ho = __float2bfloat16(wo);
                    bu.u[2 * b]     = *reinterpret_cast<ushort*>(&he);
                    bu.u[2 * b + 1] = *reinterpret_cast<ushort*>(&ho);
                }
#pragma unroll
                for (int mi = 0; mi < 4; ++mi)
                    acc[mi][nj] = __builtin_amdgcn_mfma_f32_16x16x32_bf16(
                        af[mi], bu.v, acc[mi][nj], 0, 0, 0);
            }
        }

        if (g < 3) {                            // rotate prefetch buffers
#pragma unroll
            for (int kt = 0; kt < 4; ++kt)
#pragma unroll
                for (int nj = 0; nj < 2; ++nj) qc[kt][nj] = qn[kt][nj];
#pragma unroll
            for (int nj = 0; nj < 2; ++nj) { svc[nj] = svn[nj]; zwc[nj] = zwn[nj]; }
        }
    }

    // ---- epilogue: bf16 fragment-major partials, one 64B store/thread ----
    union { ushort u[32]; u16x8_t v8[4]; } ob;
#pragma unroll
    for (int mi = 0; mi < 4; ++mi)
#pragma unroll
        for (int nj = 0; nj < 2; ++nj)
#pragma unroll
            for (int j = 0; j < 4; ++j) {
                __hip_bfloat16 h = __float2bfloat16(acc[mi][nj][j]);
                ob.u[(mi * 2 + nj) * 4 + j] = *reinterpret_cast<ushort*>(&h);
            }
    u16x8_t* pb = (u16x8_t*)part + ((size_t)(ks * 32 + nt) * 512 + threadIdx.x) * 4;
#pragma unroll
    for (int i = 0; i < 4; ++i) pb[i] = ob.v8[i];
}

// ---------------------------------------------------------------------------
// Stage B: sum 16 bf16 K-split partials (fragment layout) + bias -> out.
// Each output element written exactly once. 65536 threads.
// ---------------------------------------------------------------------------
__global__ void __launch_bounds__(256)
wol_reduce(const ushort* __restrict__ part,
           const float*  __restrict__ bias,
           float* __restrict__ out) {
    const int u   = blockIdx.x * 256 + threadIdx.x;
    const int v8  = u & 3;               // which ushort8 of the thread's 32
    const int tid = (u >> 2) & 511;      // stage-A thread id
    const int nt  = u >> 11;             // stage-A N-tile

    float s[8];
#pragma unroll
    for (int e = 0; e < 8; ++e) s[e] = 0.0f;
#pragma unroll
    for (int ks = 0; ks < KSPLIT; ++ks) {
        const u16x8_t p = *((const u16x8_t*)part +
                            (((size_t)(ks * 32 + nt) * 512 + tid) * 4 + v8));
#pragma unroll
        for (int e = 0; e < 8; ++e) {
            union { unsigned b; float f; } cv;
            cv.b = ((unsigned)(ushort)p[e]) << 16;   // bf16 -> f32 exact
            s[e] += cv.f;
        }
    }

    const int wid = tid >> 6, lane = tid & 63;
    const int ln = lane & 15, kb = lane >> 4;
#pragma unroll
    for (int e = 0; e < 8; ++e) {
        const int idx = v8 * 8 + e;                  // (mi*2+nj)*4 + j
        const int mi = idx >> 3, nj = (idx >> 2) & 1, j = idx & 3;
        const int row = mi * 16 + kb * 4 + j;
        const int col = nt * 256 + wid * 32 + nj * 16 + ln;
        out[(size_t)row * OUT_F + col] = s[e] + bias[col];
    }
}

extern "C" void kernel_launch(void* const* d_in, const int* in_sizes, int n_in,
                              void* d_out, int out_size, void* d_ws, size_t ws_size,
                              hipStream_t stream) {
    const float* x    = (const float*)d_in[0];
    const int*   qw   = (const int*)d_in[1];
    const int*   qz   = (const int*)d_in[2];
    const float* sc   = (const float*)d_in[3];
    const float* bias = (const float*)d_in[4];
    float* out = (float*)d_out;

    ushort* xb  = (ushort*)d_ws;                         // 1 MiB bf16 activations
    ushort* prt = (ushort*)((char*)d_ws + (2u << 20));   // 16 MiB bf16 partials

    (void)in_sizes; (void)n_in; (void)ws_size; (void)out_size;

    wol_xconv<<<256, 256, 0, stream>>>(x, xb);
    wol_mfma<<<512, 512, 0, stream>>>(qw, qz, sc, xb, prt);
    wol_reduce<<<256, 256, 0, stream>>>(prt, bias, out);
}